// Round 1
// baseline (521.698 us; speedup 1.0000x reference)
//
#include <hip/hip_runtime.h>

#define TINYF 1e-12f
#define EPSB  0.1f
#define EULERF 2.7182817f   // np.float32(np.e); also exp(BETA) and exp(min(BETA,1)) since BETA=1

__device__ __forceinline__ float clip1(float x) { return fminf(fmaxf(x, -1.0f), 1.0f); }
__device__ __forceinline__ float slogx(float x) { return __logf(fmaxf(x, TINYF)); }
__device__ __forceinline__ float sl1(float x) {
    float d = fabsf(x);
    return d < 1.0f ? 0.5f * d * d : d - 0.5f;   // BETA = 1
}

// f(w): xi'(w) if sg==0, sigma(w)=w*xi'(w) if sg==1.  lwp = slog(wp) hoisted.
__device__ __forceinline__ float feval(int sg, float w, float wh, float lwp) {
    float t  = clip1(slogx(w) - lwp);
    float xp = 0.5f * clip1(0.5f * (w - wh)) + __fdividef(t, fmaxf(w, TINYF));
    return sg ? w * xp : xp;
}

__device__ __forceinline__ float xieval(float w, float wh, float lwp) {
    return sl1(0.5f * (w - wh)) + sl1(lwp - slogx(w));
}

__device__ __attribute__((noinline)) float bisect(float u, float v, int sg, float wh, float lwp) {
    float fu = feval(sg, u, wh, lwp);
    float fv = feval(sg, v, wh, lwp);
    float lo = u, hi = v;
#pragma unroll 1
    for (int it = 0; it < 24; ++it) {
        bool act = (hi - lo) >= EPSB;
        if (!__any(act)) break;          // all-lane no-op from here on: identical result
        float m = 0.5f * (lo + hi);
        if (act) {
            bool pos = feval(sg, m, wh, lwp) >= 0.0f;
            if (pos) hi = m; else lo = m;
        }
    }
    float m = 0.5f * (lo + hi);
    return (fu >= 0.0f) ? u : ((fv <= 0.0f) ? v : m);
}

__device__ __attribute__((noinline)) float solve_o1(float wp, float wh, float a1, float b1) {
    float w0  = b1 - a1;
    float lwp = __logf(fmaxf(wp, TINYF));
    float rA  = bisect(fmaxf(w0, wh), wp, 0, wh, lwp);
    float ewp = EULERF * wp;
    float base = fmaxf(w0, fmaxf(wh - 2.0f, ewp));
    float disc = sqrtf(fmaxf(1.0f - __fdividef(32.0f, fmaxf(wh * wh, TINYF)), 0.0f));
    float r1 = bisect(fmaxf(w0, wp), fminf(ewp, wh), 0, wh, lwp);
    float r2 = bisect(fmaxf(fmaxf(w0, 2.0f), fmaxf(wh - 2.0f, ewp)), wh, 0, wh, lwp);
    float r3 = bisect(base, fminf(EULERF, wh), 1, wh, lwp);
    float r4 = bisect(base, fminf(fminf(ewp, wh), 0.25f * wh * (1.0f + disc)), 1, wh, lwp);
    float r5 = bisect(fmaxf(base, 0.25f * wh * (1.0f - disc)), fminf(ewp, wh), 1, wh, lwp);

    bool small = wh <= 5.656854249f;   // 4*sqrt(2)
    // argmin over candidates with first-occurrence tie-break (strict <)
    float rB = w0;
    float bestxi = xieval(w0, wh, lwp);
    float x;
    x = xieval(wh, wh, lwp);                              if (x < bestxi) { bestxi = x; rB = wh; }
    x = xieval(r1, wh, lwp);                              if (x < bestxi) { bestxi = x; rB = r1; }
    x = xieval(r2, wh, lwp);                              if (x < bestxi) { bestxi = x; rB = r2; }
    x = small  ? xieval(r3, wh, lwp) : __builtin_inff();  if (x < bestxi) { bestxi = x; rB = r3; }
    x = !small ? xieval(r4, wh, lwp) : __builtin_inff();  if (x < bestxi) { bestxi = x; rB = r4; }
    x = !small ? xieval(r5, wh, lwp) : __builtin_inff();  if (x < bestxi) { bestxi = x; rB = r5; }

    bool bA = fmaxf(w0, wh) < wp;
    bool bB = fmaxf(w0, wp) < wh;
    return bA ? rA : (bB ? rB : w0);
}

__device__ __attribute__((noinline)) void solve_o2(float dp, float wp, float a2, float b2,
                                                   float& dout, float& wout) {
    float wh1 = 2.0f * (dp - a2);
    float wh2 = 2.0f * (b2 - dp);
    float w1 = solve_o1(wp, wh1, a2, b2);
    float w2 = solve_o1(wp, wh2, a2, b2);
    float lwp = __logf(fmaxf(wp, TINYF));
    bool p1 = xieval(w1, wh1, lwp) <= xieval(w2, wh2, lwp);
    float d = p1 ? (a2 + 0.5f * w1) : (b2 - 0.5f * w2);
    float w = p1 ? w1 : w2;
    bool triv = wp >= fmaxf(wh1, wh2);
    dout = triv ? dp : d;
    wout = triv ? wp : w;
}

__device__ __forceinline__ void case_axis(float pd, float po, float td, float to,
                                          float plt, float prb, float crop,
                                          bool cl, bool cr,
                                          float& delta, float& omega) {
    float ca  = 0.5f * (plt + prb) + 0.5f;
    float da  = prb - plt + 1.0f;
    float a1r = td - 0.5f * to;
    float b1r = (crop - ca) / da;
    float wr  = solve_o1(po, 2.0f * (pd - a1r), a1r, b1r);
    float dr  = a1r + 0.5f * wr;
    float a1l = -ca / da;
    float b1l = td + 0.5f * to;
    float wl  = solve_o1(po, 2.0f * (b1l - pd), a1l, b1l);
    float dl  = b1l - 0.5f * wl;
    float db, wb;
    solve_o2(pd, po, a1l, b1r, db, wb);
    delta = (!cl && !cr) ? td : ((cr && !cl) ? dr : ((cl && !cr) ? dl : db));
    omega = (!cl && !cr) ? to : ((cr && !cl) ? wr : ((cl && !cr) ? wl : wb));
}

// cases dtype is ambiguous from the harness side (JAX bool array).
// Detect layout from the first 64 logical elements: int32 (0/1), float32 (0.0/1.0), or raw bytes.
__global__ void detect_cases_kernel(const unsigned char* __restrict__ cases, int* __restrict__ flag) {
    if (threadIdx.x == 0 && blockIdx.x == 0) {
        bool i32ok = true, f32ok = true;
        for (int g = 0; g < 64; ++g) {
            unsigned char b0 = cases[g * 4 + 0];
            unsigned char b1 = cases[g * 4 + 1];
            unsigned char b2 = cases[g * 4 + 2];
            unsigned char b3 = cases[g * 4 + 3];
            i32ok = i32ok && (b0 <= 1) && (b1 == 0) && (b2 == 0) && (b3 == 0);
            bool zf = (b2 == 0 && b3 == 0);
            bool of = (b2 == 0x80 && b3 == 0x3f);
            f32ok = f32ok && (b0 == 0) && (b1 == 0) && (zf || of);
        }
        *flag = i32ok ? 1 : (f32ok ? 2 : 0);
    }
}

__global__ __launch_bounds__(256) void cabb_kernel(
        const float4* __restrict__ pred4,
        const float4* __restrict__ targ4,
        const float4* __restrict__ prop4,
        const void*   __restrict__ cases,
        const float2* __restrict__ crop2,
        float4*       __restrict__ out4,
        const int*    __restrict__ flagp,
        int n) {
    int i = blockIdx.x * 256 + threadIdx.x;
    if (i >= n) return;

    float4 pr = pred4[i];
    float4 tg = targ4[i];
    float4 pp = prop4[i];
    float2 cs = crop2[i];

    int flag = *flagp;
    bool c0, c1, c2, c3;
    if (flag == 1) {            // int32 0/1
        int4 ci = ((const int4*)cases)[i];
        c0 = ci.x != 0; c1 = ci.y != 0; c2 = ci.z != 0; c3 = ci.w != 0;
    } else if (flag == 2) {     // float32 0.0/1.0
        float4 cf = ((const float4*)cases)[i];
        c0 = cf.x != 0.0f; c1 = cf.y != 0.0f; c2 = cf.z != 0.0f; c3 = cf.w != 0.0f;
    } else {                    // raw bool bytes
        uchar4 cb = ((const uchar4*)cases)[i];
        c0 = cb.x != 0; c1 = cb.y != 0; c2 = cb.z != 0; c3 = cb.w != 0;
    }

    float dx, wx, dy, wy;
    // axis 0: d=0, o=2, prop lt/rb = 0/2, cases lt/rb = 0/1, crop[:,0]
    case_axis(pr.x, pr.z, tg.x, tg.z, pp.x, pp.z, cs.x, c0, c1, dx, wx);
    // axis 1: d=1, o=3, prop lt/rb = 1/3, cases lt/rb = 2/3, crop[:,1]
    case_axis(pr.y, pr.w, tg.y, tg.w, pp.y, pp.w, cs.y, c2, c3, dy, wy);

    float4 o;
    o.x = sl1(pr.x - dx);
    o.y = sl1(pr.y - dy);
    o.z = sl1(pr.z - wx);
    o.w = sl1(pr.w - wy);
    out4[i] = o;
}

extern "C" void kernel_launch(void* const* d_in, const int* in_sizes, int n_in,
                              void* d_out, int out_size, void* d_ws, size_t ws_size,
                              hipStream_t stream) {
    const float* pred = (const float*)d_in[0];
    const float* targ = (const float*)d_in[1];
    const float* prop = (const float*)d_in[2];
    const void*  cases = d_in[3];
    const float* crop = (const float*)d_in[4];
    float* out = (float*)d_out;
    int n = in_sizes[0] / 4;
    int* flag = (int*)d_ws;

    detect_cases_kernel<<<1, 64, 0, stream>>>((const unsigned char*)cases, flag);
    int blocks = (n + 255) / 256;
    cabb_kernel<<<blocks, 256, 0, stream>>>(
        (const float4*)pred, (const float4*)targ, (const float4*)prop,
        cases, (const float2*)crop, (float4*)out, flag, n);
}

// Round 2
// 332.780 us; speedup vs baseline: 1.5677x; 1.5677x over previous
//
#include <hip/hip_runtime.h>

#define TINYF  1e-12f
#define EPSB   0.1f
#define EULERF 2.7182817f      // np.float32(np.e) == exp(BETA) == exp(min(BETA,1)) for BETA=1
#define SMALLWH 5.656854249f   // 4*sqrt(2)

__device__ __forceinline__ float clip1(float x) { return fminf(fmaxf(x, -1.0f), 1.0f); }
__device__ __forceinline__ float slogx(float x) { return __logf(fmaxf(x, TINYF)); }
__device__ __forceinline__ float sl1(float x) {
    float d = fabsf(x);
    return d < 1.0f ? 0.5f * d * d : d - 0.5f;   // BETA = 1
}

// f(w): xi'(w) if sg==0, sigma(w)=w*xi'(w) if sg==1.  lwp = slog(wp) hoisted.
__device__ __forceinline__ float feval(int sg, float w, float wh, float lwp) {
    float t  = clip1(slogx(w) - lwp);
    float xp = 0.5f * clip1(0.5f * (w - wh)) + __fdividef(t, fmaxf(w, TINYF));
    return sg ? w * xp : xp;
}

__device__ __forceinline__ float xieval(float w, float wh, float lwp) {
    return sl1(0.5f * (w - wh)) + sl1(lwp - slogx(w));
}

__device__ __attribute__((noinline)) float bisect(float u, float v, int sg, float wh, float lwp) {
    float fu = feval(sg, u, wh, lwp);
    float fv = feval(sg, v, wh, lwp);
    float lo = u, hi = v;
#pragma unroll 1
    for (int it = 0; it < 24; ++it) {
        bool act = (hi - lo) >= EPSB;
        if (!__any(act)) break;          // inactive iterations are no-ops: identical result
        float m = 0.5f * (lo + hi);
        if (act) {
            bool pos = feval(sg, m, wh, lwp) >= 0.0f;
            if (pos) hi = m; else lo = m;
        }
    }
    float m = 0.5f * (lo + hi);
    return (fu >= 0.0f) ? u : ((fv <= 0.0f) ? v : m);
}

// ---- path classification (matches reference's bA / bB / fallthrough) ----
// 0 = A path (1 bisection), 1 = B small, 2 = B big, 3 = trivial (w0)
__device__ __forceinline__ int classify(float wp, float wh, float w0) {
    bool bA = fmaxf(w0, wh) < wp;
    bool bB = fmaxf(w0, wp) < wh;
    if (bA) return 0;
    if (bB) return (wh <= SMALLWH) ? 1 : 2;
    return 3;
}

__device__ __forceinline__ float solveA(float wp, float wh, float w0, float lwp) {
    return bisect(fmaxf(w0, wh), wp, 0, wh, lwp);
}

__device__ __attribute__((noinline)) float solveB(float wp, float wh, float w0, float lwp, bool small) {
    float ewp  = EULERF * wp;
    float base = fmaxf(w0, fmaxf(wh - 2.0f, ewp));
    float r1 = bisect(fmaxf(w0, wp), fminf(ewp, wh), 0, wh, lwp);
    float r2 = bisect(fmaxf(fmaxf(w0, 2.0f), fmaxf(wh - 2.0f, ewp)), wh, 0, wh, lwp);
    // argmin with first-occurrence tie-break, candidate order [w0, wh, r1, r2, r3|r4, r5]
    float rB = w0, best = xieval(w0, wh, lwp), x;
    x = xieval(wh, wh, lwp); if (x < best) { best = x; rB = wh; }
    x = xieval(r1, wh, lwp); if (x < best) { best = x; rB = r1; }
    x = xieval(r2, wh, lwp); if (x < best) { best = x; rB = r2; }
    if (small) {
        float r3 = bisect(base, fminf(EULERF, wh), 1, wh, lwp);
        x = xieval(r3, wh, lwp); if (x < best) { best = x; rB = r3; }
    } else {
        float disc = sqrtf(fmaxf(1.0f - __fdividef(32.0f, fmaxf(wh * wh, TINYF)), 0.0f));
        float r4 = bisect(base, fminf(fminf(ewp, wh), 0.25f * wh * (1.0f + disc)), 1, wh, lwp);
        float r5 = bisect(fmaxf(base, 0.25f * wh * (1.0f - disc)), fminf(ewp, wh), 1, wh, lwp);
        x = xieval(r4, wh, lwp); if (x < best) { best = x; rB = r4; }
        x = xieval(r5, wh, lwp); if (x < best) { best = x; rB = r5; }
    }
    return rB;
}

// ---- per-axis parameter extraction / bracket computation ----
__device__ __forceinline__ void axis_params(const float4& pr, const float4& tg,
                                            const float4& pp, const float2& cs, int axis,
                                            float& pd, float& po, float& td, float& to,
                                            float& ca, float& da, float& crop) {
    pd = axis ? pr.y : pr.x;  po = axis ? pr.w : pr.z;
    td = axis ? tg.y : tg.x;  to = axis ? tg.w : tg.z;
    float plt = axis ? pp.y : pp.x, prb = axis ? pp.w : pp.z;
    ca = 0.5f * (plt + prb) + 0.5f;
    da = prb - plt + 1.0f;
    crop = axis ? cs.y : cs.x;
}

// kind: 0 = R, 1 = L, 2 = O2-first (wh1), 3 = O2-second (wh2)
__device__ __forceinline__ void solve_brackets(int kind, float pd, float po, float td, float to,
                                               float ca, float da, float crop,
                                               float& wp, float& wh, float& a1, float& b1) {
    wp = po;
    if (kind == 0)      { a1 = td - 0.5f * to; b1 = (crop - ca) / da; wh = 2.0f * (pd - a1); }
    else if (kind == 1) { a1 = -ca / da;       b1 = td + 0.5f * to;   wh = 2.0f * (b1 - pd); }
    else if (kind == 2) { a1 = -ca / da;       b1 = (crop - ca) / da; wh = 2.0f * (pd - a1); }
    else                { a1 = -ca / da;       b1 = (crop - ca) / da; wh = 2.0f * (b1 - pd); }
}

__device__ __forceinline__ void load_cases(const void* cases, int flag, int i,
                                           bool& c0, bool& c1, bool& c2, bool& c3) {
    if (flag == 1) {            // int32 0/1
        int4 ci = ((const int4*)cases)[i];
        c0 = ci.x != 0; c1 = ci.y != 0; c2 = ci.z != 0; c3 = ci.w != 0;
    } else if (flag == 2) {     // float32 0.0/1.0
        float4 cf = ((const float4*)cases)[i];
        c0 = cf.x != 0.0f; c1 = cf.y != 0.0f; c2 = cf.z != 0.0f; c3 = cf.w != 0.0f;
    } else {                    // raw bool bytes
        uchar4 cb = ((const uchar4*)cases)[i];
        c0 = cb.x != 0; c1 = cb.y != 0; c2 = cb.z != 0; c3 = cb.w != 0;
    }
}

// ---- misc small kernels ----
__global__ void detect_cases_kernel(const unsigned char* __restrict__ cases, int* __restrict__ flag) {
    if (threadIdx.x == 0 && blockIdx.x == 0) {
        bool i32ok = true, f32ok = true;
        for (int g = 0; g < 64; ++g) {
            unsigned char b0 = cases[g * 4 + 0];
            unsigned char b1 = cases[g * 4 + 1];
            unsigned char b2 = cases[g * 4 + 2];
            unsigned char b3 = cases[g * 4 + 3];
            i32ok = i32ok && (b0 <= 1) && (b1 == 0) && (b2 == 0) && (b3 == 0);
            bool zf = (b2 == 0 && b3 == 0);
            bool of = (b2 == 0x80 && b3 == 0x3f);
            f32ok = f32ok && (b0 == 0) && (b1 == 0) && (zf || of);
        }
        *flag = i32ok ? 1 : (f32ok ? 2 : 0);
    }
}

__global__ void k_zero(int* cnt) { if (threadIdx.x < 3) cnt[threadIdx.x] = 0; }

// ---- K1: classify + emit task records (block-aggregated atomics) ----
__global__ __launch_bounds__(256) void k_classify(
        const float4* __restrict__ pred4, const float4* __restrict__ targ4,
        const float4* __restrict__ prop4, const void* __restrict__ cases,
        const float2* __restrict__ crop2, const int* __restrict__ flagp,
        float* __restrict__ resW, int* __restrict__ cnt,
        int* baseB0, int* baseB1, int* baseB2,
        int dir0, int dir1, int dir2, int map1, int map2, int n) {
    __shared__ int lcnt[3];
    __shared__ int gbase[3];
    if (threadIdx.x < 3) lcnt[threadIdx.x] = 0;
    __syncthreads();
    int i = blockIdx.x * 256 + threadIdx.x;
    int bk0 = -1, bk1 = -1, bk2 = -1, bk3 = -1;
    int rc0 = 0, rc1 = 0, rc2 = 0, rc3 = 0;
    int ps0 = 0, ps1 = 0, ps2 = 0, ps3 = 0;
    if (i < n) {
        float4 pr = pred4[i], tg = targ4[i], pp = prop4[i];
        float2 cs = crop2[i];
        bool c0, c1, c2, c3;
        load_cases(cases, *flagp, i, c0, c1, c2, c3);
#pragma unroll
        for (int axis = 0; axis < 2; ++axis) {
            bool cl = axis ? c2 : c0;
            bool cr = axis ? c3 : c1;
            if (!cl && !cr) continue;
            float pd, po, td, to, ca, da, crop;
            axis_params(pr, tg, pp, cs, axis, pd, po, td, to, ca, da, crop);
            int kindFirst;
            bool two = false;
            if (cr && !cl) kindFirst = 0;
            else if (cl && !cr) kindFirst = 1;
            else {
                float wp, wh1, wh2, a1, b1;
                solve_brackets(2, pd, po, td, to, ca, da, crop, wp, wh1, a1, b1);
                solve_brackets(3, pd, po, td, to, ca, da, crop, wp, wh2, a1, b1);
                if (po >= fmaxf(wh1, wh2)) continue;    // trivial o2: (dp, wp), no tasks
                kindFirst = 2; two = true;
            }
            {
                float wp, wh, a1, b1;
                solve_brackets(kindFirst, pd, po, td, to, ca, da, crop, wp, wh, a1, b1);
                float w0 = b1 - a1;
                int cls = classify(wp, wh, w0);
                if (cls == 3) resW[(i << 2) | (axis << 1)] = w0;
                else {
                    int b = (cls == 0) ? 0 : ((cls == 1) ? map1 : map2);
                    int rc = (i << 3) | (axis << 2) | kindFirst;
                    if (axis == 0) { bk0 = b; rc0 = rc; } else { bk2 = b; rc2 = rc; }
                }
            }
            if (two) {
                float wp, wh, a1, b1;
                solve_brackets(3, pd, po, td, to, ca, da, crop, wp, wh, a1, b1);
                float w0 = b1 - a1;
                int cls = classify(wp, wh, w0);
                if (cls == 3) resW[(i << 2) | (axis << 1) | 1] = w0;
                else {
                    int b = (cls == 0) ? 0 : ((cls == 1) ? map1 : map2);
                    int rc = (i << 3) | (axis << 2) | 3;
                    if (axis == 0) { bk1 = b; rc1 = rc; } else { bk3 = b; rc3 = rc; }
                }
            }
        }
    }
    // wave-aggregated reservation into LDS counters (all threads participate)
    auto reserve = [&](int b, int& posOut) {
#pragma unroll
        for (int bkt = 0; bkt < 3; ++bkt) {
            bool mine = (b == bkt);
            unsigned long long mask = __ballot(mine);
            if (mine) {
                int lane = threadIdx.x & 63;
                int off = (int)__popcll(mask & ((1ull << lane) - 1ull));
                int wb = 0;
                if (off == 0) wb = atomicAdd(&lcnt[bkt], (int)__popcll(mask));
                int leader = (int)__ffsll((unsigned long long)mask) - 1;
                wb = __shfl(wb, leader);
                posOut = wb + off;
            }
        }
    };
    reserve(bk0, ps0); reserve(bk1, ps1); reserve(bk2, ps2); reserve(bk3, ps3);
    __syncthreads();
    if (threadIdx.x < 3) gbase[threadIdx.x] = atomicAdd(&cnt[threadIdx.x], lcnt[threadIdx.x]);
    __syncthreads();
    auto writeRec = [&](int b, int pos, int rec) {
        if (b < 0) return;
        int p = gbase[b] + pos;
        if (b == 0)      baseB0[dir0 * p] = rec;
        else if (b == 1) baseB1[dir1 * p] = rec;
        else             baseB2[dir2 * p] = rec;
    };
    writeRec(bk0, ps0, rc0); writeRec(bk1, ps1, rc1);
    writeRec(bk2, ps2, rc2); writeRec(bk3, ps3, rc3);
}

// ---- K2: coherent solver kernels. BUCKET: 0=A, 1=Bsmall, 2=Bbig, 3=Bmixed ----
template <int BUCKET>
__global__ __launch_bounds__(256) void k_solve(
        const float4* __restrict__ pred4, const float4* __restrict__ targ4,
        const float4* __restrict__ prop4, const float2* __restrict__ crop2,
        const int* __restrict__ recs, int dir, const int* __restrict__ cntp,
        float* __restrict__ resW) {
    int count = *cntp;
    int stride = gridDim.x * 256;
    for (int t = blockIdx.x * 256 + threadIdx.x; t < count; t += stride) {
        int rec = recs[dir * t];
        int box = rec >> 3, axis = (rec >> 2) & 1, kind = rec & 3;
        float4 pr = pred4[box], tg = targ4[box], pp = prop4[box];
        float2 cs = crop2[box];
        float pd, po, td, to, ca, da, crop;
        axis_params(pr, tg, pp, cs, axis, pd, po, td, to, ca, da, crop);
        float wp, wh, a1, b1;
        solve_brackets(kind, pd, po, td, to, ca, da, crop, wp, wh, a1, b1);
        float w0 = b1 - a1;
        float lwp = __logf(fmaxf(wp, TINYF));
        float w;
        if (BUCKET == 0) {
            w = solveA(wp, wh, w0, lwp);
        } else {
            bool small = (BUCKET == 1) ? true : ((BUCKET == 2) ? false : (wh <= SMALLWH));
            w = solveB(wp, wh, w0, lwp, small);
        }
        int slot = (kind == 3) ? 1 : 0;
        resW[(box << 2) | (axis << 1) | slot] = w;
    }
}

// ---- K3: combine + final loss.  outw aliases the resW scratch (d_out). ----
__global__ __launch_bounds__(256) void k_combine(
        const float4* __restrict__ pred4, const float4* __restrict__ targ4,
        const float4* __restrict__ prop4, const void* __restrict__ cases,
        const float2* __restrict__ crop2, const int* __restrict__ flagp,
        float* outw, int n) {
    int i = blockIdx.x * 256 + threadIdx.x;
    if (i >= n) return;
    float4 pr = pred4[i], tg = targ4[i], pp = prop4[i];
    float2 cs = crop2[i];
    bool c0, c1, c2, c3;
    load_cases(cases, *flagp, i, c0, c1, c2, c3);
    float lab[4];
#pragma unroll
    for (int axis = 0; axis < 2; ++axis) {
        bool cl = axis ? c2 : c0;
        bool cr = axis ? c3 : c1;
        float pd, po, td, to, ca, da, crop;
        axis_params(pr, tg, pp, cs, axis, pd, po, td, to, ca, da, crop);
        float delta, omega;
        if (!cl && !cr) { delta = td; omega = to; }
        else if (cr && !cl) {
            float w = outw[(i << 2) | (axis << 1)];
            float a1r = td - 0.5f * to;
            delta = a1r + 0.5f * w; omega = w;
        } else if (cl && !cr) {
            float w = outw[(i << 2) | (axis << 1)];
            float b1l = td + 0.5f * to;
            delta = b1l - 0.5f * w; omega = w;
        } else {
            float a1l = -ca / da, b1r = (crop - ca) / da;
            float wh1 = 2.0f * (pd - a1l), wh2 = 2.0f * (b1r - pd);
            if (po >= fmaxf(wh1, wh2)) { delta = pd; omega = po; }
            else {
                float w1 = outw[(i << 2) | (axis << 1)];
                float w2 = outw[(i << 2) | (axis << 1) | 1];
                float lwp = __logf(fmaxf(po, TINYF));
                bool p1 = xieval(w1, wh1, lwp) <= xieval(w2, wh2, lwp);
                delta = p1 ? (a1l + 0.5f * w1) : (b1r - 0.5f * w2);
                omega = p1 ? w1 : w2;
            }
        }
        lab[axis] = delta;
        lab[2 + axis] = omega;
    }
    float4 o;
    o.x = sl1(pr.x - lab[0]);
    o.y = sl1(pr.y - lab[1]);
    o.z = sl1(pr.z - lab[2]);
    o.w = sl1(pr.w - lab[3]);
    ((float4*)outw)[i] = o;   // each thread reads its own slots above before this write
}

// ---- fallback monolithic kernel (ws too small) — classify-dispatched solve_o1 ----
__device__ float solve_o1_mono(float wp, float wh, float a1, float b1) {
    float w0 = b1 - a1;
    float lwp = __logf(fmaxf(wp, TINYF));
    int cls = classify(wp, wh, w0);
    if (cls == 0) return solveA(wp, wh, w0, lwp);
    if (cls == 3) return w0;
    return solveB(wp, wh, w0, lwp, cls == 1);
}

__global__ __launch_bounds__(256) void cabb_mono(
        const float4* __restrict__ pred4, const float4* __restrict__ targ4,
        const float4* __restrict__ prop4, const void* __restrict__ cases,
        const float2* __restrict__ crop2, float* outw,
        const int* __restrict__ flagp, int n) {
    int i = blockIdx.x * 256 + threadIdx.x;
    if (i >= n) return;
    float4 pr = pred4[i], tg = targ4[i], pp = prop4[i];
    float2 cs = crop2[i];
    bool c0, c1, c2, c3;
    load_cases(cases, *flagp, i, c0, c1, c2, c3);
    float lab[4];
#pragma unroll
    for (int axis = 0; axis < 2; ++axis) {
        bool cl = axis ? c2 : c0;
        bool cr = axis ? c3 : c1;
        float pd, po, td, to, ca, da, crop;
        axis_params(pr, tg, pp, cs, axis, pd, po, td, to, ca, da, crop);
        float delta, omega;
        if (!cl && !cr) { delta = td; omega = to; }
        else if (cr && !cl) {
            float wp, wh, a1, b1;
            solve_brackets(0, pd, po, td, to, ca, da, crop, wp, wh, a1, b1);
            float w = solve_o1_mono(wp, wh, a1, b1);
            delta = a1 + 0.5f * w; omega = w;
        } else if (cl && !cr) {
            float wp, wh, a1, b1;
            solve_brackets(1, pd, po, td, to, ca, da, crop, wp, wh, a1, b1);
            float w = solve_o1_mono(wp, wh, a1, b1);
            delta = b1 - 0.5f * w; omega = w;
        } else {
            float wp, wh1, wh2, a1, b1;
            solve_brackets(2, pd, po, td, to, ca, da, crop, wp, wh1, a1, b1);
            solve_brackets(3, pd, po, td, to, ca, da, crop, wp, wh2, a1, b1);
            if (po >= fmaxf(wh1, wh2)) { delta = pd; omega = po; }
            else {
                float w1 = solve_o1_mono(wp, wh1, a1, b1);
                float w2 = solve_o1_mono(wp, wh2, a1, b1);
                float lwp = __logf(fmaxf(po, TINYF));
                bool p1 = xieval(w1, wh1, lwp) <= xieval(w2, wh2, lwp);
                delta = p1 ? (a1 + 0.5f * w1) : (b1 - 0.5f * w2);
                omega = p1 ? w1 : w2;
            }
        }
        lab[axis] = delta;
        lab[2 + axis] = omega;
    }
    float4 o;
    o.x = sl1(pr.x - lab[0]);
    o.y = sl1(pr.y - lab[1]);
    o.z = sl1(pr.z - lab[2]);
    o.w = sl1(pr.w - lab[3]);
    ((float4*)outw)[i] = o;
}

extern "C" void kernel_launch(void* const* d_in, const int* in_sizes, int n_in,
                              void* d_out, int out_size, void* d_ws, size_t ws_size,
                              hipStream_t stream) {
    const float4* pred = (const float4*)d_in[0];
    const float4* targ = (const float4*)d_in[1];
    const float4* prop = (const float4*)d_in[2];
    const void*   cases = d_in[3];
    const float2* crop = (const float2*)d_in[4];
    float* outw = (float*)d_out;
    int n = in_sizes[0] / 4;

    int* cnt  = (int*)d_ws;        // cnt[0..2] bucket counters
    int* flag = cnt + 3;
    int* region = (int*)((char*)d_ws + 256);
    size_t cap = (size_t)4 * n;                    // max total tasks
    size_t needFull = 256 + cap * 4 * 2;           // two int regions
    size_t needHalf = 256 + cap * 4;               // one int region

    detect_cases_kernel<<<1, 64, 0, stream>>>((const unsigned char*)cases, flag);

    int nb = (n + 255) / 256;
    const int GS = 3072;

    if (ws_size >= needFull) {
        int* arr1 = region;              // A grows up; Bsmall grows down from arr1[cap-1]
        int* arr2 = region + cap;        // Bbig grows up
        k_zero<<<1, 64, 0, stream>>>(cnt);
        k_classify<<<nb, 256, 0, stream>>>(pred, targ, prop, cases, crop, flag,
                                           outw, cnt,
                                           arr1, arr1 + cap - 1, arr2,
                                           +1, -1, +1, 1, 2, n);
        k_solve<0><<<GS, 256, 0, stream>>>(pred, targ, prop, crop, arr1, +1, cnt + 0, outw);
        k_solve<1><<<GS, 256, 0, stream>>>(pred, targ, prop, crop, arr1 + cap - 1, -1, cnt + 1, outw);
        k_solve<2><<<GS, 256, 0, stream>>>(pred, targ, prop, crop, arr2, +1, cnt + 2, outw);
        k_combine<<<nb, 256, 0, stream>>>(pred, targ, prop, cases, crop, flag, outw, n);
    } else if (ws_size >= needHalf) {
        int* arr1 = region;              // A grows up; B(mixed) grows down
        k_zero<<<1, 64, 0, stream>>>(cnt);
        k_classify<<<nb, 256, 0, stream>>>(pred, targ, prop, cases, crop, flag,
                                           outw, cnt,
                                           arr1, arr1 + cap - 1, arr1 + cap - 1,
                                           +1, -1, -1, 1, 1, n);
        k_solve<0><<<GS, 256, 0, stream>>>(pred, targ, prop, crop, arr1, +1, cnt + 0, outw);
        k_solve<3><<<GS, 256, 0, stream>>>(pred, targ, prop, crop, arr1 + cap - 1, -1, cnt + 1, outw);
        k_combine<<<nb, 256, 0, stream>>>(pred, targ, prop, cases, crop, flag, outw, n);
    } else {
        cabb_mono<<<nb, 256, 0, stream>>>(pred, targ, prop, cases, crop, outw, flag, n);
    }
}

// Round 4
// 196.641 us; speedup vs baseline: 2.6530x; 1.6923x over previous
//
#include <hip/hip_runtime.h>

#define TINYF   1e-12f
#define EPSB    0.1f
#define EULERF  2.7182817f      // np.float32(np.e) == exp(BETA) == exp(min(BETA,1)) for BETA=1
#define SMALLWH 5.656854249f    // 4*sqrt(2)

__device__ __forceinline__ float clip1(float x) { return fminf(fmaxf(x, -1.0f), 1.0f); }
__device__ __forceinline__ float slogx(float x) { return __logf(fmaxf(x, TINYF)); }
__device__ __forceinline__ float sl1(float x) {
    float d = fabsf(x);
    return d < 1.0f ? 0.5f * d * d : d - 0.5f;   // BETA = 1
}

// h(w) = max(w,TINY) * xi'(w): sign-equivalent to xi'(w) everywhere (max(w,TINY)>0),
// and value-equal (real arithmetic) to sigma(w)=w*xi'(w) at all sigma-bisect points
// (those always have w > 0.1). One log, no divide.
__device__ __forceinline__ float heval(float w, float wh, float lwp) {
    float t  = clip1(slogx(w) - lwp);
    float c2 = clip1(0.5f * (w - wh));
    return fmaf(0.5f * c2, fmaxf(w, TINYF), t);
}

__device__ __forceinline__ float xieval(float w, float wh, float lwp) {
    return sl1(0.5f * (w - wh)) + sl1(lwp - slogx(w));
}

__device__ __forceinline__ float bisect(float u, float v, float wh, float lwp) {
    float fu = heval(u, wh, lwp);
    float fv = heval(v, wh, lwp);
    float lo = u, hi = v;
#pragma unroll 1
    for (int it = 0; it < 24; ++it) {
        bool act = (hi - lo) >= EPSB;
        if (!__any(act)) break;          // inactive iterations are no-ops: identical result
        float m = 0.5f * (lo + hi);
        if (act) {
            if (heval(m, wh, lwp) >= 0.0f) hi = m; else lo = m;
        }
    }
    float m = 0.5f * (lo + hi);
    return (fu >= 0.0f) ? u : ((fv <= 0.0f) ? v : m);
}

// 0 = A path (1 bisection), 1 = B small, 2 = B big, 3 = trivial (w0)
__device__ __forceinline__ int classify(float wp, float wh, float w0) {
    bool bA = fmaxf(w0, wh) < wp;
    bool bB = fmaxf(w0, wp) < wh;
    if (bA) return 0;
    if (bB) return (wh <= SMALLWH) ? 1 : 2;
    return 3;
}

__device__ __forceinline__ float solveA(float wp, float wh, float w0, float lwp) {
    return bisect(fmaxf(w0, wh), wp, wh, lwp);
}

__device__ __forceinline__ float solveB(float wp, float wh, float w0, float lwp, bool small) {
    float ewp  = EULERF * wp;
    float base = fmaxf(w0, fmaxf(wh - 2.0f, ewp));
    float r1 = bisect(fmaxf(w0, wp), fminf(ewp, wh), wh, lwp);
    float r2 = bisect(fmaxf(fmaxf(w0, 2.0f), fmaxf(wh - 2.0f, ewp)), wh, wh, lwp);
    // argmin with first-occurrence tie-break, candidate order [w0, wh, r1, r2, r3 | r4, r5]
    float rB = w0, best = xieval(w0, wh, lwp), x;
    x = xieval(wh, wh, lwp); if (x < best) { best = x; rB = wh; }
    x = xieval(r1, wh, lwp); if (x < best) { best = x; rB = r1; }
    x = xieval(r2, wh, lwp); if (x < best) { best = x; rB = r2; }
    if (small) {
        float r3 = bisect(base, fminf(EULERF, wh), wh, lwp);
        x = xieval(r3, wh, lwp); if (x < best) { best = x; rB = r3; }
    } else {
        float disc = sqrtf(fmaxf(1.0f - __fdividef(32.0f, fmaxf(wh * wh, TINYF)), 0.0f));
        float r4 = bisect(base, fminf(fminf(ewp, wh), 0.25f * wh * (1.0f + disc)), wh, lwp);
        float r5 = bisect(fmaxf(base, 0.25f * wh * (1.0f - disc)), fminf(ewp, wh), wh, lwp);
        x = xieval(r4, wh, lwp); if (x < best) { best = x; rB = r4; }
        x = xieval(r5, wh, lwp); if (x < best) { best = x; rB = r5; }
    }
    return rB;
}

__device__ __forceinline__ void load_cases(const void* cases, int flag, int i,
                                           bool& c0, bool& c1, bool& c2, bool& c3) {
    if (flag == 1) {            // int32 0/1
        int4 ci = ((const int4*)cases)[i];
        c0 = ci.x != 0; c1 = ci.y != 0; c2 = ci.z != 0; c3 = ci.w != 0;
    } else if (flag == 2) {     // float32 0.0/1.0
        float4 cf = ((const float4*)cases)[i];
        c0 = cf.x != 0.0f; c1 = cf.y != 0.0f; c2 = cf.z != 0.0f; c3 = cf.w != 0.0f;
    } else {                    // raw bool bytes
        uchar4 cb = ((const uchar4*)cases)[i];
        c0 = cb.x != 0; c1 = cb.y != 0; c2 = cb.z != 0; c3 = cb.w != 0;
    }
}

__global__ void detect_cases_kernel(const unsigned char* __restrict__ cases, int* __restrict__ flag) {
    if (threadIdx.x == 0 && blockIdx.x == 0) {
        bool i32ok = true, f32ok = true;
        for (int g = 0; g < 64; ++g) {
            unsigned char b0 = cases[g * 4 + 0];
            unsigned char b1 = cases[g * 4 + 1];
            unsigned char b2 = cases[g * 4 + 2];
            unsigned char b3 = cases[g * 4 + 3];
            i32ok = i32ok && (b0 <= 1) && (b1 == 0) && (b2 == 0) && (b3 == 0);
            bool zf = (b2 == 0 && b3 == 0);
            bool of = (b2 == 0x80 && b3 == 0x3f);
            f32ok = f32ok && (b0 == 0) && (b1 == 0) && (zf || of);
        }
        *flag = i32ok ? 1 : (f32ok ? 2 : 0);
    }
}

// ---- fused kernel: load -> classify -> block-local compaction -> coherent solve -> combine ----
__global__ __launch_bounds__(256) void cabb_fused(
        const float4* __restrict__ pred4, const float4* __restrict__ targ4,
        const float4* __restrict__ prop4, const void* __restrict__ cases,
        const float2* __restrict__ crop2, const int* __restrict__ flagp,
        float4* __restrict__ out4, int n) {
    __shared__ float tWp[1024], tWh[1024], tW0[1024];
    __shared__ unsigned short tDst[1024];
    __shared__ float resW[1024];     // [local box][4] slots
    __shared__ int cnt[3];
    __shared__ int base[3];

    int tid = threadIdx.x;
    int i = blockIdx.x * 256 + tid;
    if (tid < 3) cnt[tid] = 0;
    __syncthreads();

    bool valid = i < n;
    float4 pr = {0,0,0,0}, tg = {0,0,0,0};
    float caA[2] = {0,0}, daA[2] = {1,1}, cropA[2] = {0,0};
    bool clA[2] = {false,false}, crA[2] = {false,false};

    // staged tasks: slot k = axis*2 + sec; all statically indexed
    float sWp[4], sWh[4], sW0[4];
    int sCls[4], sPos[4];
#pragma unroll
    for (int k = 0; k < 4; ++k) { sCls[k] = -1; sPos[k] = 0; sWp[k] = 0; sWh[k] = 0; sW0[k] = 0; }

    if (valid) {
        pr = pred4[i]; tg = targ4[i];
        float4 pp = prop4[i];
        float2 cs = crop2[i];
        bool c0, c1, c2, c3;
        load_cases(cases, *flagp, i, c0, c1, c2, c3);
        clA[0] = c0; crA[0] = c1; clA[1] = c2; crA[1] = c3;
        caA[0] = 0.5f * (pp.x + pp.z) + 0.5f;  daA[0] = pp.z - pp.x + 1.0f;  cropA[0] = cs.x;
        caA[1] = 0.5f * (pp.y + pp.w) + 0.5f;  daA[1] = pp.w - pp.y + 1.0f;  cropA[1] = cs.y;
    }

    // ---- classify, stage tasks ----
#pragma unroll
    for (int axis = 0; axis < 2; ++axis) {
        if (!valid) continue;
        bool L = clA[axis], R = crA[axis];
        if (!(L || R)) continue;
        float pd = axis ? pr.y : pr.x, po = axis ? pr.w : pr.z;
        float td = axis ? tg.y : tg.x, to = axis ? tg.w : tg.z;
        int k0 = axis * 2, k1 = axis * 2 + 1;
        if (R && !L) {
            float a1 = td - 0.5f * to;
            float b1 = __fdividef(cropA[axis] - caA[axis], daA[axis]);
            float wh = 2.0f * (pd - a1), w0 = b1 - a1;
            int c = classify(po, wh, w0);
            if (c == 3) resW[(tid << 2) | (axis << 1)] = w0;
            else { sCls[k0] = c; sWp[k0] = po; sWh[k0] = wh; sW0[k0] = w0; }
        } else if (L && !R) {
            float a1 = __fdividef(-caA[axis], daA[axis]);
            float b1 = td + 0.5f * to;
            float wh = 2.0f * (b1 - pd), w0 = b1 - a1;
            int c = classify(po, wh, w0);
            if (c == 3) resW[(tid << 2) | (axis << 1)] = w0;
            else { sCls[k0] = c; sWp[k0] = po; sWh[k0] = wh; sW0[k0] = w0; }
        } else {
            float a1l = __fdividef(-caA[axis], daA[axis]);
            float b1r = __fdividef(cropA[axis] - caA[axis], daA[axis]);
            float wh1 = 2.0f * (pd - a1l), wh2 = 2.0f * (b1r - pd);
            if (po < fmaxf(wh1, wh2)) {           // non-trivial o2: two solves
                float w0 = b1r - a1l;
                int ck0 = classify(po, wh1, w0);
                if (ck0 == 3) resW[(tid << 2) | (axis << 1)] = w0;
                else { sCls[k0] = ck0; sWp[k0] = po; sWh[k0] = wh1; sW0[k0] = w0; }
                int ck1 = classify(po, wh2, w0);
                if (ck1 == 3) resW[(tid << 2) | (axis << 1) | 1] = w0;
                else { sCls[k1] = ck1; sWp[k1] = po; sWh[k1] = wh2; sW0[k1] = w0; }
            }
        }
    }

    // ---- wave-aggregated reservation into LDS class counters ----
#pragma unroll
    for (int k = 0; k < 4; ++k) {
#pragma unroll
        for (int c = 0; c < 3; ++c) {
            bool mine = (sCls[k] == c);
            unsigned long long mask = __ballot(mine);
            if (mine) {
                int lane = tid & 63;
                int off = (int)__popcll(mask & ((1ull << lane) - 1ull));
                int leader = (int)__ffsll((unsigned long long)mask) - 1;
                int wb = 0;
                if (lane == leader) wb = atomicAdd(&cnt[c], (int)__popcll(mask));
                wb = __shfl(wb, leader);
                sPos[k] = wb + off;
            }
        }
    }
    __syncthreads();
    if (tid == 0) { base[0] = 0; base[1] = cnt[0]; base[2] = cnt[0] + cnt[1]; }
    __syncthreads();
#pragma unroll
    for (int k = 0; k < 4; ++k) {
        if (sCls[k] >= 0) {
            int p = base[sCls[k]] + sPos[k];
            tWp[p] = sWp[k]; tWh[p] = sWh[k]; tW0[p] = sW0[k];
            tDst[p] = (unsigned short)((tid << 2) | k);
        }
    }
    __syncthreads();

    // ---- coherent solve: [0,nA) = A, [nA,nAB1) = B small, [nAB1,total) = B big ----
    int nA = base[1], nAB1 = base[2], total = base[2] + cnt[2];
    for (int t0 = 0; t0 < total; t0 += 256) {
        int t = t0 + tid;
        if (t < total) {
            float wp = tWp[t], wh = tWh[t], w0 = tW0[t];
            float lwp = __logf(fmaxf(wp, TINYF));
            float w;
            if (t < nA) w = solveA(wp, wh, w0, lwp);
            else        w = solveB(wp, wh, w0, lwp, t < nAB1);
            resW[tDst[t]] = w;
        }
    }
    __syncthreads();

    // ---- combine + loss ----
    if (valid) {
        float labd[2], labw[2];
#pragma unroll
        for (int axis = 0; axis < 2; ++axis) {
            bool L = clA[axis], R = crA[axis];
            float pd = axis ? pr.y : pr.x, po = axis ? pr.w : pr.z;
            float td = axis ? tg.y : tg.x, to = axis ? tg.w : tg.z;
            float delta, omega;
            if (!L && !R) { delta = td; omega = to; }
            else if (R && !L) {
                float w = resW[(tid << 2) | (axis << 1)];
                float a1 = td - 0.5f * to;
                delta = a1 + 0.5f * w; omega = w;
            } else if (L && !R) {
                float w = resW[(tid << 2) | (axis << 1)];
                float b1 = td + 0.5f * to;
                delta = b1 - 0.5f * w; omega = w;
            } else {
                float a1l = __fdividef(-caA[axis], daA[axis]);
                float b1r = __fdividef(cropA[axis] - caA[axis], daA[axis]);
                float wh1 = 2.0f * (pd - a1l), wh2 = 2.0f * (b1r - pd);
                if (po >= fmaxf(wh1, wh2)) { delta = pd; omega = po; }
                else {
                    float w1 = resW[(tid << 2) | (axis << 1)];
                    float w2 = resW[(tid << 2) | (axis << 1) | 1];
                    float lwp = __logf(fmaxf(po, TINYF));
                    bool p1 = xieval(w1, wh1, lwp) <= xieval(w2, wh2, lwp);
                    delta = p1 ? (a1l + 0.5f * w1) : (b1r - 0.5f * w2);
                    omega = p1 ? w1 : w2;
                }
            }
            labd[axis] = delta; labw[axis] = omega;
        }
        float4 o;
        o.x = sl1(pr.x - labd[0]);
        o.y = sl1(pr.y - labd[1]);
        o.z = sl1(pr.z - labw[0]);
        o.w = sl1(pr.w - labw[1]);
        out4[i] = o;
    }
}

extern "C" void kernel_launch(void* const* d_in, const int* in_sizes, int n_in,
                              void* d_out, int out_size, void* d_ws, size_t ws_size,
                              hipStream_t stream) {
    const float4* pred = (const float4*)d_in[0];
    const float4* targ = (const float4*)d_in[1];
    const float4* prop = (const float4*)d_in[2];
    const void*   cases = d_in[3];
    const float2* crop = (const float2*)d_in[4];
    float4* out = (float4*)d_out;
    int n = in_sizes[0] / 4;
    int* flag = (int*)d_ws;

    detect_cases_kernel<<<1, 64, 0, stream>>>((const unsigned char*)cases, flag);
    int nb = (n + 255) / 256;
    cabb_fused<<<nb, 256, 0, stream>>>(pred, targ, prop, cases, crop, flag, out, n);
}

// Round 6
// 188.688 us; speedup vs baseline: 2.7649x; 1.0422x over previous
//
#include <hip/hip_runtime.h>

#define TINYF   1e-12f
#define EPSB    0.1f
#define EULERF  2.7182817f      // np.float32(np.e) == exp(BETA) == exp(min(BETA,1)) for BETA=1
#define SMALLWH 5.656854249f    // 4*sqrt(2)

__device__ __forceinline__ float clip1(float x) { return fminf(fmaxf(x, -1.0f), 1.0f); }
__device__ __forceinline__ float slogx(float x) { return __logf(fmaxf(x, TINYF)); }
__device__ __forceinline__ float sl1(float x) {
    float d = fabsf(x);
    return d < 1.0f ? 0.5f * d * d : d - 0.5f;   // BETA = 1
}

// h(w) = max(w,TINY) * xi'(w): sign-equivalent to xi'(w) everywhere (max(w,TINY)>0),
// and value-equal (real arithmetic) to sigma(w)=w*xi'(w) at all sigma-bisect points.
__device__ __forceinline__ float heval(float w, float wh, float lwp) {
    float t  = clip1(slogx(w) - lwp);
    float c2 = clip1(0.5f * (w - wh));
    return fmaf(0.5f * c2, fmaxf(w, TINYF), t);
}

__device__ __forceinline__ float xieval(float w, float wh, float lwp) {
    return sl1(0.5f * (w - wh)) + sl1(lwp - slogx(w));
}

__device__ __forceinline__ float bisect(float u, float v, float wh, float lwp) {
    float fu = heval(u, wh, lwp);
    float fv = heval(v, wh, lwp);
    float lo = u, hi = v;
#pragma unroll 1
    for (int it = 0; it < 24; ++it) {
        bool act = (hi - lo) >= EPSB;
        if (!__any(act)) break;          // inactive iterations are no-ops: identical result
        float m = 0.5f * (lo + hi);
        if (act) {
            if (heval(m, wh, lwp) >= 0.0f) hi = m; else lo = m;
        }
    }
    float m = 0.5f * (lo + hi);
    return (fu >= 0.0f) ? u : ((fv <= 0.0f) ? v : m);
}

// 0 = A path (1 bisection), 1 = B small, 2 = B big, 3 = trivial (w0)
__device__ __forceinline__ int classify(float wp, float wh, float w0) {
    bool bA = fmaxf(w0, wh) < wp;
    bool bB = fmaxf(w0, wp) < wh;
    if (bA) return 0;
    if (bB) return (wh <= SMALLWH) ? 1 : 2;
    return 3;
}

__device__ __forceinline__ float solveA(float wp, float wh, float w0, float lwp) {
    return bisect(fmaxf(w0, wh), wp, wh, lwp);
}

__device__ __forceinline__ float solveB(float wp, float wh, float w0, float lwp, bool small) {
    float ewp  = EULERF * wp;
    float base = fmaxf(w0, fmaxf(wh - 2.0f, ewp));
    float r1 = bisect(fmaxf(w0, wp), fminf(ewp, wh), wh, lwp);
    float r2 = bisect(fmaxf(fmaxf(w0, 2.0f), fmaxf(wh - 2.0f, ewp)), wh, wh, lwp);
    // argmin with first-occurrence tie-break, candidate order [w0, wh, r1, r2, r3 | r4, r5]
    float rB = w0, best = xieval(w0, wh, lwp), x;
    x = xieval(wh, wh, lwp); if (x < best) { best = x; rB = wh; }
    x = xieval(r1, wh, lwp); if (x < best) { best = x; rB = r1; }
    x = xieval(r2, wh, lwp); if (x < best) { best = x; rB = r2; }
    if (small) {
        float r3 = bisect(base, fminf(EULERF, wh), wh, lwp);
        x = xieval(r3, wh, lwp); if (x < best) { best = x; rB = r3; }
    } else {
        float disc = sqrtf(fmaxf(1.0f - __fdividef(32.0f, fmaxf(wh * wh, TINYF)), 0.0f));
        float r4 = bisect(base, fminf(fminf(ewp, wh), 0.25f * wh * (1.0f + disc)), wh, lwp);
        float r5 = bisect(fmaxf(base, 0.25f * wh * (1.0f - disc)), fminf(ewp, wh), wh, lwp);
        x = xieval(r4, wh, lwp); if (x < best) { best = x; rB = r4; }
        x = xieval(r5, wh, lwp); if (x < best) { best = x; rB = r5; }
    }
    return rB;
}

__device__ __forceinline__ void load_cases(const void* cases, int flag, int i,
                                           bool& c0, bool& c1, bool& c2, bool& c3) {
    if (flag == 1) {            // int32 0/1
        int4 ci = ((const int4*)cases)[i];
        c0 = ci.x != 0; c1 = ci.y != 0; c2 = ci.z != 0; c3 = ci.w != 0;
    } else if (flag == 2) {     // float32 0.0/1.0
        float4 cf = ((const float4*)cases)[i];
        c0 = cf.x != 0.0f; c1 = cf.y != 0.0f; c2 = cf.z != 0.0f; c3 = cf.w != 0.0f;
    } else {                    // raw bool bytes
        uchar4 cb = ((const uchar4*)cases)[i];
        c0 = cb.x != 0; c1 = cb.y != 0; c2 = cb.z != 0; c3 = cb.w != 0;
    }
}

// ---- fused kernel: detect -> load -> classify -> block-local compaction -> solve -> combine ----
__global__ __launch_bounds__(256) void cabb_fused(
        const float4* __restrict__ pred4, const float4* __restrict__ targ4,
        const float4* __restrict__ prop4, const void* __restrict__ cases,
        const float2* __restrict__ crop2,
        float4* __restrict__ out4, int n) {
    __shared__ float tWp[1024], tWh[1024], tW0[1024];
    __shared__ unsigned short tDst[1024];
    __shared__ float resW[1024];     // slot k*256 + tid
    __shared__ int cnt[3];
    __shared__ int base[3];
    __shared__ int sFlag;

    int tid = threadIdx.x;
    int i = blockIdx.x * 256 + tid;
    if (tid < 3) cnt[tid] = 0;

    // ---- dtype detection (wave 0, all 64 lanes active; first 64 groups, L2-cached) ----
    if (tid < 64) {
        uchar4 cb = ((const uchar4*)cases)[tid];
        bool i32ok = (cb.x <= 1) && (cb.y == 0) && (cb.z == 0) && (cb.w == 0);
        bool f32ok = (cb.x == 0) && (cb.y == 0) &&
                     ((cb.z == 0 && cb.w == 0) || (cb.z == 0x80 && cb.w == 0x3f));
        unsigned long long m32 = __ballot(i32ok);
        unsigned long long mf  = __ballot(f32ok);
        if (tid == 0) sFlag = (m32 == ~0ull) ? 1 : ((mf == ~0ull) ? 2 : 0);
    }
    __syncthreads();
    int flag = sFlag;

    bool valid = i < n;
    float4 pr = {0,0,0,0}, tg = {0,0,0,0};
    float caA[2] = {0,0}, daA[2] = {1,1}, cropA[2] = {0,0};
    bool clA[2] = {false,false}, crA[2] = {false,false};

    // staged tasks: slot k = axis*2 + sec; all statically indexed
    float sWp[4], sWh[4], sW0[4];
    int sCls[4], sPos[4];
#pragma unroll
    for (int k = 0; k < 4; ++k) { sCls[k] = -1; sPos[k] = 0; sWp[k] = 0; sWh[k] = 0; sW0[k] = 0; }

    if (valid) {
        pr = pred4[i]; tg = targ4[i];
        float4 pp = prop4[i];
        float2 cs = crop2[i];
        bool c0, c1, c2, c3;
        load_cases(cases, flag, i, c0, c1, c2, c3);
        clA[0] = c0; crA[0] = c1; clA[1] = c2; crA[1] = c3;
        caA[0] = 0.5f * (pp.x + pp.z) + 0.5f;  daA[0] = pp.z - pp.x + 1.0f;  cropA[0] = cs.x;
        caA[1] = 0.5f * (pp.y + pp.w) + 0.5f;  daA[1] = pp.w - pp.y + 1.0f;  cropA[1] = cs.y;
    }

    // ---- classify, stage tasks ----
#pragma unroll
    for (int axis = 0; axis < 2; ++axis) {
        if (!valid) continue;
        bool L = clA[axis], R = crA[axis];
        if (!(L || R)) continue;
        float pd = axis ? pr.y : pr.x, po = axis ? pr.w : pr.z;
        float td = axis ? tg.y : tg.x, to = axis ? tg.w : tg.z;
        int k0 = axis * 2, k1 = axis * 2 + 1;
        if (R && !L) {
            float a1 = td - 0.5f * to;
            float b1 = __fdividef(cropA[axis] - caA[axis], daA[axis]);
            float wh = 2.0f * (pd - a1), w0 = b1 - a1;
            int c = classify(po, wh, w0);
            if (c == 3) resW[k0 * 256 + tid] = w0;
            else { sCls[k0] = c; sWp[k0] = po; sWh[k0] = wh; sW0[k0] = w0; }
        } else if (L && !R) {
            float a1 = __fdividef(-caA[axis], daA[axis]);
            float b1 = td + 0.5f * to;
            float wh = 2.0f * (b1 - pd), w0 = b1 - a1;
            int c = classify(po, wh, w0);
            if (c == 3) resW[k0 * 256 + tid] = w0;
            else { sCls[k0] = c; sWp[k0] = po; sWh[k0] = wh; sW0[k0] = w0; }
        } else {
            float a1l = __fdividef(-caA[axis], daA[axis]);
            float b1r = __fdividef(cropA[axis] - caA[axis], daA[axis]);
            float wh1 = 2.0f * (pd - a1l), wh2 = 2.0f * (b1r - pd);
            if (po < fmaxf(wh1, wh2)) {           // non-trivial o2: two solves
                float w0 = b1r - a1l;
                int ck0 = classify(po, wh1, w0);
                if (ck0 == 3) resW[k0 * 256 + tid] = w0;
                else { sCls[k0] = ck0; sWp[k0] = po; sWh[k0] = wh1; sW0[k0] = w0; }
                int ck1 = classify(po, wh2, w0);
                if (ck1 == 3) resW[k1 * 256 + tid] = w0;
                else { sCls[k1] = ck1; sWp[k1] = po; sWh[k1] = wh2; sW0[k1] = w0; }
            }
        }
    }

    // ---- direct LDS-atomic reservation (order within class is irrelevant) ----
#pragma unroll
    for (int k = 0; k < 4; ++k) {
        if (sCls[k] >= 0) sPos[k] = atomicAdd(&cnt[sCls[k]], 1);
    }
    __syncthreads();
    if (tid == 0) { base[0] = 0; base[1] = cnt[0]; base[2] = cnt[0] + cnt[1]; }
    __syncthreads();
#pragma unroll
    for (int k = 0; k < 4; ++k) {
        if (sCls[k] >= 0) {
            int p = base[sCls[k]] + sPos[k];
            tWp[p] = sWp[k]; tWh[p] = sWh[k]; tW0[p] = sW0[k];
            tDst[p] = (unsigned short)(k * 256 + tid);
        }
    }
    __syncthreads();

    // ---- coherent solve: [0,nA) = A, [nA,nAB1) = B small, [nAB1,total) = B big ----
    int nA = base[1], nAB1 = base[2], total = base[2] + cnt[2];
    for (int t0 = 0; t0 < total; t0 += 256) {
        int t = t0 + tid;
        if (t < total) {
            float wp = tWp[t], wh = tWh[t], w0 = tW0[t];
            float lwp = __logf(fmaxf(wp, TINYF));
            float w;
            if (t < nA) w = solveA(wp, wh, w0, lwp);
            else        w = solveB(wp, wh, w0, lwp, t < nAB1);
            resW[tDst[t]] = w;
        }
    }
    __syncthreads();

    // ---- combine + loss ----
    if (valid) {
        float labd[2], labw[2];
#pragma unroll
        for (int axis = 0; axis < 2; ++axis) {
            bool L = clA[axis], R = crA[axis];
            float pd = axis ? pr.y : pr.x, po = axis ? pr.w : pr.z;
            float td = axis ? tg.y : tg.x, to = axis ? tg.w : tg.z;
            float delta, omega;
            if (!L && !R) { delta = td; omega = to; }
            else if (R && !L) {
                float w = resW[(axis * 2) * 256 + tid];
                float a1 = td - 0.5f * to;
                delta = a1 + 0.5f * w; omega = w;
            } else if (L && !R) {
                float w = resW[(axis * 2) * 256 + tid];
                float b1 = td + 0.5f * to;
                delta = b1 - 0.5f * w; omega = w;
            } else {
                float a1l = __fdividef(-caA[axis], daA[axis]);
                float b1r = __fdividef(cropA[axis] - caA[axis], daA[axis]);
                float wh1 = 2.0f * (pd - a1l), wh2 = 2.0f * (b1r - pd);
                if (po >= fmaxf(wh1, wh2)) { delta = pd; omega = po; }
                else {
                    float w1 = resW[(axis * 2) * 256 + tid];
                    float w2 = resW[(axis * 2 + 1) * 256 + tid];
                    float lwp = __logf(fmaxf(po, TINYF));
                    bool p1 = xieval(w1, wh1, lwp) <= xieval(w2, wh2, lwp);
                    delta = p1 ? (a1l + 0.5f * w1) : (b1r - 0.5f * w2);
                    omega = p1 ? w1 : w2;
                }
            }
            labd[axis] = delta; labw[axis] = omega;
        }
        float4 o;
        o.x = sl1(pr.x - labd[0]);
        o.y = sl1(pr.y - labd[1]);
        o.z = sl1(pr.z - labw[0]);
        o.w = sl1(pr.w - labw[1]);
        out4[i] = o;
    }
}

extern "C" void kernel_launch(void* const* d_in, const int* in_sizes, int n_in,
                              void* d_out, int out_size, void* d_ws, size_t ws_size,
                              hipStream_t stream) {
    const float4* pred = (const float4*)d_in[0];
    const float4* targ = (const float4*)d_in[1];
    const float4* prop = (const float4*)d_in[2];
    const void*   cases = d_in[3];
    const float2* crop = (const float2*)d_in[4];
    float4* out = (float4*)d_out;
    int n = in_sizes[0] / 4;

    int nb = (n + 255) / 256;
    cabb_fused<<<nb, 256, 0, stream>>>(pred, targ, prop, cases, crop, out, n);
}

// Round 11
// 179.320 us; speedup vs baseline: 2.9093x; 1.0522x over previous
//
#include <hip/hip_runtime.h>

#define TINYF   1e-12f
#define EPSB    0.1f
#define EULERF  2.7182817f      // np.float32(np.e) == exp(BETA) == exp(min(BETA,1)) for BETA=1
#define SMALLWH 5.656854249f    // 4*sqrt(2)
#define LN2F    0.69314718f

__device__ __forceinline__ float clip1(float x) { return fminf(fmaxf(x, -1.0f), 1.0f); }
__device__ __forceinline__ float sl1(float x) {
    float d = fabsf(x);
    return d < 1.0f ? 0.5f * d * d : d - 0.5f;   // BETA = 1
}
__device__ __forceinline__ float l2x(float x) { return __log2f(fmaxf(x, TINYF)); }

// generic h(w) = 0.5*clip1(0.5(w-wh))*max(w,TINY) + clip1(ln w - lwp); sign == xi'(w) sign,
// value == sigma(w) at all sigma points (w>0 there). lwp = natural log of wp.
__device__ __forceinline__ float heval(float w, float wh, float lwp) {
    float t = clip1(fmaf(l2x(w), LN2F, -lwp));
    float c = clip1(0.5f * (w - wh));
    return fmaf(0.5f * c, fmaxf(w, TINYF), t);
}
// log-free h for w >= e*wp (log term saturated at +1); caller guarantees w > 0.
__device__ __forceinline__ float hq(float w, float wh) {
    float c = clip1(0.5f * (w - wh));
    return fmaf(0.5f * c, w, 1.0f);
}

__device__ __forceinline__ float xieval(float w, float wh, float lwp) {
    float t = fmaf(l2x(w), LN2F, -lwp);     // sl1 is even: sl1(lwp-lnw) == sl1(lnw-lwp)
    return sl1(0.5f * (w - wh)) + sl1(t);
}

// generic bisect (rA, r1): log per eval
__device__ __forceinline__ float bisect_g(float u, float v, float wh, float lwp) {
    float fu = heval(u, wh, lwp);
    float fv = heval(v, wh, lwp);
    float lo = u, hi = v;
#pragma unroll 1
    for (int it = 0; it < 24; ++it) {
        bool act = (hi - lo) >= EPSB;
        if (!__any(act)) break;          // inactive iterations are no-ops: identical result
        float m = 0.5f * (lo + hi);
        if (act) {
            if (heval(m, wh, lwp) >= 0.0f) hi = m; else lo = m;
        }
    }
    float m = 0.5f * (lo + hi);
    return (fu >= 0.0f) ? u : ((fv <= 0.0f) ? v : m);
}

// log-free quadratic bisect (r2, r3): all interior points have w >= e*wp (saturated log)
// and w in (wh-2, wh) (linear clip). fv supplied by caller (v may be < e*wp).
__device__ __forceinline__ float bisect_q(float u, float v, float wh, float fv) {
    float fu = hq(u, wh);
    float lo = u, hi = v;
#pragma unroll 1
    for (int it = 0; it < 24; ++it) {
        bool act = (hi - lo) >= EPSB;
        if (!__any(act)) break;
        float m = 0.5f * (lo + hi);
        if (act) {
            if (hq(m, wh) >= 0.0f) hi = m; else lo = m;
        }
    }
    float m = 0.5f * (lo + hi);
    return (fu >= 0.0f) ? u : ((fv <= 0.0f) ? v : m);
}

// 0 = A path (1 bisection), 1 = B small, 2 = B big, 3 = trivial (w0)
__device__ __forceinline__ int classify(float wp, float wh, float w0) {
    bool bA = fmaxf(w0, wh) < wp;
    bool bB = fmaxf(w0, wp) < wh;
    if (bA) return 0;
    if (bB) return (wh <= SMALLWH) ? 1 : 2;
    return 3;
}

__device__ __forceinline__ float solveA(float wp, float wh, float w0, float lwp) {
    return bisect_g(fmaxf(w0, wh), wp, wh, lwp);
}

__device__ __forceinline__ float solveB(float wp, float wh, float w0, float lwp, bool small) {
    float ewp  = EULERF * wp;
    float base = fmaxf(w0, fmaxf(wh - 2.0f, ewp));
    float lnwh = l2x(wh) * LN2F;
    // r1: genuinely in the log-linear region
    float r1 = bisect_g(fmaxf(w0, wp), fminf(ewp, wh), wh, lwp);
    // r2: log-free quadratic; fv2 = heval(wh) = clip1(ln wh - lwp) (c-term is exactly 0)
    float fv2 = clip1(lnwh - lwp);
    float r2 = bisect_q(fmaxf(fmaxf(w0, 2.0f), fmaxf(wh - 2.0f, ewp)), wh, wh, fv2);

    // argmin with first-occurrence tie-break, candidate order [w0, wh, r1, r2, r3 | r4, r5]
    float rB = w0, best = xieval(w0, wh, lwp), x;
    x = sl1(lwp - lnwh);                       // xieval(wh): first term sl1(0)=0
    if (x < best) { best = x; rB = wh; }
    x = xieval(r1, wh, lwp); if (x < best) { best = x; rB = r1; }
    x = xieval(r2, wh, lwp); if (x < best) { best = x; rB = r2; }
    if (small) {
        float v3 = fminf(EULERF, wh);
        float r3 = bisect_q(base, v3, wh, heval(v3, wh, lwp));
        x = xieval(r3, wh, lwp); if (x < best) { best = x; rB = r3; }
    } else {
        float disc = sqrtf(fmaxf(1.0f - __fdividef(32.0f, fmaxf(wh * wh, TINYF)), 0.0f));
        // r4/r5: hi <= e*wp <= lo structurally -> zero iterations; endpoint signs only
        float v4 = fminf(fminf(ewp, wh), 0.25f * wh * (1.0f + disc));
        float fu4 = hq(base, wh), fv4 = heval(v4, wh, lwp);
        float r4 = (fu4 >= 0.0f) ? base : ((fv4 <= 0.0f) ? v4 : 0.5f * (base + v4));
        float u5 = fmaxf(base, 0.25f * wh * (1.0f - disc));
        float v5 = fminf(ewp, wh);
        float fu5 = hq(u5, wh), fv5 = heval(v5, wh, lwp);
        float r5 = (fu5 >= 0.0f) ? u5 : ((fv5 <= 0.0f) ? v5 : 0.5f * (u5 + v5));
        x = xieval(r4, wh, lwp); if (x < best) { best = x; rB = r4; }
        x = xieval(r5, wh, lwp); if (x < best) { best = x; rB = r5; }
    }
    return rB;
}

__device__ __forceinline__ void load_cases(const void* cases, int flag, int i,
                                           bool& c0, bool& c1, bool& c2, bool& c3) {
    if (flag == 1) {            // int32 0/1
        int4 ci = ((const int4*)cases)[i];
        c0 = ci.x != 0; c1 = ci.y != 0; c2 = ci.z != 0; c3 = ci.w != 0;
    } else if (flag == 2) {     // float32 0.0/1.0
        float4 cf = ((const float4*)cases)[i];
        c0 = cf.x != 0.0f; c1 = cf.y != 0.0f; c2 = cf.z != 0.0f; c3 = cf.w != 0.0f;
    } else {                    // raw bool bytes
        uchar4 cb = ((const uchar4*)cases)[i];
        c0 = cb.x != 0; c1 = cb.y != 0; c2 = cb.z != 0; c3 = cb.w != 0;
    }
}

// ---- fused kernel: detect -> load -> classify -> block-local compaction -> solve -> combine ----
__global__ __launch_bounds__(256) void cabb_fused(
        const float4* __restrict__ pred4, const float4* __restrict__ targ4,
        const float4* __restrict__ prop4, const void* __restrict__ cases,
        const float2* __restrict__ crop2,
        float4* __restrict__ out4, int n) {
    __shared__ float tWp[1024], tWh[1024], tW0[1024];
    __shared__ unsigned short tDst[1024];
    __shared__ float resW[1024];     // slot k*256 + tid
    __shared__ int cnt[3];
    __shared__ int base[3];
    __shared__ int sFlag;

    int tid = threadIdx.x;
    int i = blockIdx.x * 256 + tid;
    if (tid < 3) cnt[tid] = 0;

    // ---- dtype detection (wave 0; first 64 4-byte groups, L2-cached) ----
    if (tid < 64) {
        uchar4 cb = ((const uchar4*)cases)[tid];
        bool i32ok = (cb.x <= 1) && (cb.y == 0) && (cb.z == 0) && (cb.w == 0);
        bool f32ok = (cb.x == 0) && (cb.y == 0) &&
                     ((cb.z == 0 && cb.w == 0) || (cb.z == 0x80 && cb.w == 0x3f));
        unsigned long long m32 = __ballot(i32ok);
        unsigned long long mf  = __ballot(f32ok);
        if (tid == 0) sFlag = (m32 == ~0ull) ? 1 : ((mf == ~0ull) ? 2 : 0);
    }
    __syncthreads();
    int flag = sFlag;

    bool valid = i < n;
    float4 pr = {0,0,0,0}, tg = {0,0,0,0};
    float caA[2] = {0,0}, rdA[2] = {1,1}, cropA[2] = {0,0};
    bool clA[2] = {false,false}, crA[2] = {false,false};

    // staged tasks: slot k = axis*2 + sec; all statically indexed
    float sWp[4], sWh[4], sW0[4];
    int sCls[4], sPos[4];
#pragma unroll
    for (int k = 0; k < 4; ++k) { sCls[k] = -1; sPos[k] = 0; sWp[k] = 0; sWh[k] = 0; sW0[k] = 0; }

    if (valid) {
        pr = pred4[i]; tg = targ4[i];
        float4 pp = prop4[i];
        float2 cs = crop2[i];
        bool c0, c1, c2, c3;
        load_cases(cases, flag, i, c0, c1, c2, c3);
        clA[0] = c0; crA[0] = c1; clA[1] = c2; crA[1] = c3;
        caA[0] = 0.5f * (pp.x + pp.z) + 0.5f;  rdA[0] = __fdividef(1.0f, pp.z - pp.x + 1.0f);  cropA[0] = cs.x;
        caA[1] = 0.5f * (pp.y + pp.w) + 0.5f;  rdA[1] = __fdividef(1.0f, pp.w - pp.y + 1.0f);  cropA[1] = cs.y;
    }

    // ---- classify, stage tasks ----
#pragma unroll
    for (int axis = 0; axis < 2; ++axis) {
        if (!valid) continue;
        bool L = clA[axis], R = crA[axis];
        if (!(L || R)) continue;
        float pd = axis ? pr.y : pr.x, po = axis ? pr.w : pr.z;
        float td = axis ? tg.y : tg.x, to = axis ? tg.w : tg.z;
        float b1r = (cropA[axis] - caA[axis]) * rdA[axis];
        float a1l = -caA[axis] * rdA[axis];
        int k0 = axis * 2, k1 = axis * 2 + 1;
        if (L != R) {
            // branch-free single-sided setup
            float a1 = R ? (td - 0.5f * to) : a1l;
            float b1 = R ? b1r : (td + 0.5f * to);
            float wh = 2.0f * (R ? (pd - a1) : (b1 - pd));
            float w0 = b1 - a1;
            int c = classify(po, wh, w0);
            if (c == 3) resW[k0 * 256 + tid] = w0;
            else { sCls[k0] = c; sWp[k0] = po; sWh[k0] = wh; sW0[k0] = w0; }
        } else {
            float wh1 = 2.0f * (pd - a1l), wh2 = 2.0f * (b1r - pd);
            if (po < fmaxf(wh1, wh2)) {           // non-trivial o2: two solves
                float w0 = b1r - a1l;
                int ck0 = classify(po, wh1, w0);
                if (ck0 == 3) resW[k0 * 256 + tid] = w0;
                else { sCls[k0] = ck0; sWp[k0] = po; sWh[k0] = wh1; sW0[k0] = w0; }
                int ck1 = classify(po, wh2, w0);
                if (ck1 == 3) resW[k1 * 256 + tid] = w0;
                else { sCls[k1] = ck1; sWp[k1] = po; sWh[k1] = wh2; sW0[k1] = w0; }
            }
        }
    }

    // ---- direct LDS-atomic reservation (order within class is irrelevant) ----
#pragma unroll
    for (int k = 0; k < 4; ++k) {
        if (sCls[k] >= 0) sPos[k] = atomicAdd(&cnt[sCls[k]], 1);
    }
    __syncthreads();
    if (tid == 0) { base[0] = 0; base[1] = cnt[0]; base[2] = cnt[0] + cnt[1]; }
    __syncthreads();
#pragma unroll
    for (int k = 0; k < 4; ++k) {
        if (sCls[k] >= 0) {
            int p = base[sCls[k]] + sPos[k];
            tWp[p] = sWp[k]; tWh[p] = sWh[k]; tW0[p] = sW0[k];
            tDst[p] = (unsigned short)(k * 256 + tid);
        }
    }
    __syncthreads();

    // ---- coherent solve: [0,nA) = A, [nA,nAB1) = B small, [nAB1,total) = B big ----
    int nA = base[1], nAB1 = base[2], total = base[2] + cnt[2];
    for (int t0 = 0; t0 < total; t0 += 256) {
        int t = t0 + tid;
        if (t < total) {
            float wp = tWp[t], wh = tWh[t], w0 = tW0[t];
            float lwp = l2x(wp) * LN2F;
            float w;
            if (t < nA) w = solveA(wp, wh, w0, lwp);
            else        w = solveB(wp, wh, w0, lwp, t < nAB1);
            resW[tDst[t]] = w;
        }
    }
    __syncthreads();

    // ---- combine + loss ----
    if (valid) {
        float labd[2], labw[2];
#pragma unroll
        for (int axis = 0; axis < 2; ++axis) {
            bool L = clA[axis], R = crA[axis];
            float pd = axis ? pr.y : pr.x, po = axis ? pr.w : pr.z;
            float td = axis ? tg.y : tg.x, to = axis ? tg.w : tg.z;
            float delta, omega;
            if (!L && !R) { delta = td; omega = to; }
            else if (L != R) {
                float w = resW[(axis * 2) * 256 + tid];
                // R: (td - 0.5to) + 0.5w ; L: (td + 0.5to) - 0.5w
                float a = R ? (td - 0.5f * to) : (td + 0.5f * to);
                delta = R ? (a + 0.5f * w) : (a - 0.5f * w);
                omega = w;
            } else {
                float b1r = (cropA[axis] - caA[axis]) * rdA[axis];
                float a1l = -caA[axis] * rdA[axis];
                float wh1 = 2.0f * (pd - a1l), wh2 = 2.0f * (b1r - pd);
                if (po >= fmaxf(wh1, wh2)) { delta = pd; omega = po; }
                else {
                    float w1 = resW[(axis * 2) * 256 + tid];
                    float w2 = resW[(axis * 2 + 1) * 256 + tid];
                    float lwp = l2x(po) * LN2F;
                    bool p1 = xieval(w1, wh1, lwp) <= xieval(w2, wh2, lwp);
                    delta = p1 ? (a1l + 0.5f * w1) : (b1r - 0.5f * w2);
                    omega = p1 ? w1 : w2;
                }
            }
            labd[axis] = delta; labw[axis] = omega;
        }
        float4 o;
        o.x = sl1(pr.x - labd[0]);
        o.y = sl1(pr.y - labd[1]);
        o.z = sl1(pr.z - labw[0]);
        o.w = sl1(pr.w - labw[1]);
        out4[i] = o;
    }
}

extern "C" void kernel_launch(void* const* d_in, const int* in_sizes, int n_in,
                              void* d_out, int out_size, void* d_ws, size_t ws_size,
                              hipStream_t stream) {
    const float4* pred = (const float4*)d_in[0];
    const float4* targ = (const float4*)d_in[1];
    const float4* prop = (const float4*)d_in[2];
    const void*   cases = d_in[3];
    const float2* crop = (const float2*)d_in[4];
    float4* out = (float4*)d_out;
    int n = in_sizes[0] / 4;

    int nb = (n + 255) / 256;
    cabb_fused<<<nb, 256, 0, stream>>>(pred, targ, prop, cases, crop, out, n);
}